// Round 4
// baseline (805.163 us; speedup 1.0000x reference)
//
#include <hip/hip_runtime.h>

// ELBO for the chromatin "Decoding" model — round 4.
// vs round 3:
//  * ZERO global atomics (R1-R3 hid ~200-400us of scattered device atomicAdds
//    below the top-5 cutoff). Cuts-by-gene AND fragments-by-cell are sorted
//    with a two-level no-atomic counting sort (LDS hist -> column scan ->
//    LDS-rank scatter). Fragment counts are built in LDS inside the Poisson
//    kernel; the 8MB global counts array + memset + hist kernel are deleted.
//  * cuts_v4: 32-lane group per cut, 1 component/lane, weights loaded into
//    w[64] VGPRs from GLOBAL (R3's LDS-sourced w0/w1 got rematerialized as
//    in-loop ds_reads: VGPR_Count=84 proved it). launch_bounds(256,4) caps
//    at 128 VGPR -> 4 waves/SIMD.

#define TPB 256
#define CHUNK 16384
#define MAXG 4096
#define MAXN 1024
#define HALF_LOG_2PI 0.9189385332046727f

// 256-thread block reduction; valid in thread 0 only.
static __device__ __forceinline__ float block_reduce(float v) {
  #pragma unroll
  for (int off = 32; off > 0; off >>= 1) v += __shfl_down(v, off, 64);
  __shared__ float wsum[4];
  if ((threadIdx.x & 63) == 0) wsum[threadIdx.x >> 6] = v;
  __syncthreads();
  return (threadIdx.x == 0) ? (wsum[0] + wsum[1] + wsum[2] + wsum[3]) : 0.f;
}

// ---------------- A: gene params ----------------
__global__ __launch_bounds__(TPB) void gene_params_kernel(
    const int* __restrict__ genes_oi,
    const float* __restrict__ loc_w, const float* __restrict__ scale_w,
    const float* __restrict__ logit_w,
    float4* __restrict__ gp, int G) {
  int idx = blockIdx.x * TPB + threadIdx.x;       // over G*32
  if (idx >= G * 32) return;
  int g = idx >> 5, c = idx & 31;
  long long gene = genes_oi[g];
  float lv = loc_w[gene * 32 + c];
  float loc = 1.f / (1.f + __expf(-lv));
  float sc = 1e-5f + __expf(scale_w[gene * 32 + c]);
  gp[idx] = make_float4(loc, 1.f / sc, -__logf(sc) - HALF_LOG_2PI, logit_w[gene * 32 + c]);
}

// ---------------- S1: per-chunk LDS histograms (cuts by g_d, frags by n) ----
__global__ __launch_bounds__(TPB) void sort_pass1(
    const int* __restrict__ cxg, const int* __restrict__ lix,
    unsigned* __restrict__ cntC, unsigned* __restrict__ cntF,
    int K, int F, unsigned G, unsigned N) {
  __shared__ unsigned hC[MAXG];
  __shared__ unsigned hF[MAXN];
  for (int t = threadIdx.x; t < MAXG; t += TPB) hC[t] = 0;
  for (int t = threadIdx.x; t < MAXN; t += TPB) hF[t] = 0;
  __syncthreads();
  int i0 = blockIdx.x * CHUNK;
  for (int t = threadIdx.x; t < CHUNK; t += TPB) {
    int i = i0 + t;
    if (i < K) { unsigned ix = (unsigned)cxg[i]; atomicAdd(&hC[ix % G], 1u); }
    if (i < F) { unsigned v = (unsigned)lix[i]; atomicAdd(&hF[v / G], 1u); }
  }
  __syncthreads();
  size_t b = blockIdx.x;
  for (unsigned t = threadIdx.x; t < G; t += TPB) cntC[b * G + t] = hC[t];
  for (unsigned t = threadIdx.x; t < N; t += TPB) cntF[b * N + t] = hF[t];
}

// ---------------- S2a: per-bin column scan over chunks ----------------
__global__ __launch_bounds__(TPB) void colscan_kernel(
    unsigned* __restrict__ cntC, unsigned* __restrict__ cntF,
    unsigned* __restrict__ totC, unsigned* __restrict__ totF,
    int B, unsigned G, unsigned N) {
  unsigned t = blockIdx.x * TPB + threadIdx.x;
  if (t < G) {
    unsigned run = 0;
    for (int b = 0; b < B; b++) {
      unsigned v = cntC[(size_t)b * G + t];
      cntC[(size_t)b * G + t] = run;
      run += v;
    }
    totC[t] = run;
  } else if (t < G + N) {
    unsigned s = t - G;
    unsigned run = 0;
    for (int b = 0; b < B; b++) {
      unsigned v = cntF[(size_t)b * N + s];
      cntF[(size_t)b * N + s] = run;
      run += v;
    }
    totF[s] = run;
  }
}

// ---------------- S2b: single-block exclusive scans -> base offsets ---------
static __device__ void scan_dev(const unsigned* __restrict__ cnt,
                                unsigned* __restrict__ offs, int S, unsigned M) {
  __shared__ unsigned tmp[TPB];
  __shared__ unsigned base;
  if (threadIdx.x == 0) base = 0;
  __syncthreads();
  for (int c0 = 0; c0 < S; c0 += TPB) {
    int i = c0 + (int)threadIdx.x;
    unsigned v = (i < S) ? cnt[i] : 0u;
    tmp[threadIdx.x] = v;
    __syncthreads();
    for (int d = 1; d < TPB; d <<= 1) {
      unsigned t = (threadIdx.x >= (unsigned)d) ? tmp[threadIdx.x - d] : 0u;
      __syncthreads();
      tmp[threadIdx.x] += t;
      __syncthreads();
    }
    unsigned excl = tmp[threadIdx.x] - v + base;
    if (i < S) offs[i] = excl;
    __syncthreads();
    if (threadIdx.x == TPB - 1) base = excl + v;
    __syncthreads();
  }
  if (threadIdx.x == 0) offs[S] = M;
  __syncthreads();
}

__global__ __launch_bounds__(TPB) void scan2_kernel(
    const unsigned* __restrict__ totC, unsigned* __restrict__ baseC, int SC, unsigned K,
    const unsigned* __restrict__ totF, unsigned* __restrict__ baseF, int SF, unsigned F) {
  scan_dev(totC, baseC, SC, K);
  scan_dev(totF, baseF, SF, F);
}

// ---------------- S3: LDS-rank scatter (both sorts) ----------------
__global__ __launch_bounds__(TPB) void sort_pass3(
    const int* __restrict__ cxg, const int* __restrict__ lix,
    const float* __restrict__ xc, const int* __restrict__ gix,
    const unsigned* __restrict__ cntC, const unsigned* __restrict__ cntF,
    const unsigned* __restrict__ baseC, const unsigned* __restrict__ baseF,
    float2* __restrict__ pl, unsigned* __restrict__ fpl,
    int K, int F, unsigned G, unsigned N) {
  __shared__ unsigned cC[MAXG];
  __shared__ unsigned cF[MAXN];
  for (int t = threadIdx.x; t < MAXG; t += TPB) cC[t] = 0;
  for (int t = threadIdx.x; t < MAXN; t += TPB) cF[t] = 0;
  __syncthreads();
  int i0 = blockIdx.x * CHUNK;
  size_t b = blockIdx.x;
  for (int t = threadIdx.x; t < CHUNK; t += TPB) {
    int i = i0 + t;
    if (i < K) {
      unsigned ix = (unsigned)cxg[i];
      unsigned g = ix % G, n = ix / G;
      unsigned r = atomicAdd(&cC[g], 1u);
      unsigned pos = baseC[g] + cntC[b * G + g] + r;
      pl[pos] = make_float2(xc[i], __uint_as_float((n << 16) | (unsigned)gix[i]));
    }
    if (i < F) {
      unsigned v = (unsigned)lix[i];
      unsigned n = v / G, g = v - n * G;
      unsigned r = atomicAdd(&cF[n], 1u);
      fpl[baseF[n] + cntF[b * N + n] + r] = (n << 16) | g;
    }
  }
}

// ---------------- D: cuts v4 — 32-lane group/cut, weights in VGPRs ----------
__global__ __launch_bounds__(TPB, 4) void cuts_v4(
    const float2* __restrict__ pl, const float* __restrict__ latent,
    const int* __restrict__ genes_oi, const float* __restrict__ logit_weight,
    const float4* __restrict__ gp, const unsigned* __restrict__ baseC,
    float* __restrict__ partials, unsigned G) {
  const int g = blockIdx.x;
  const int cc = threadIdx.x & 31;            // component (0..31)
  const int grp = (threadIdx.x >> 5) & 1;     // group within wave
  const int wv = threadIdx.x >> 6;

  // per-lane weight column from GLOBAL (compiler cannot demote to LDS)
  const float* Wg = logit_weight + (size_t)genes_oi[g] * 2048 + cc;
  float w[64];
  #pragma unroll
  for (int l = 0; l < 64; l++) w[l] = Wg[l * 32];

  const unsigned start = baseC[g], end = baseC[g + 1];
  float lm = 0.f;
  for (unsigned kk = start + wv * 2 + grp; kk < end; kk += 8) {
    float2 p = pl[kk];
    float x = p.x;
    unsigned u = __float_as_uint(p.y);
    const float4* latr = (const float4*)(latent + (size_t)(u >> 16) * 64);
    float acc = 0.f;
    #pragma unroll
    for (int i = 0; i < 16; i++) {
      float4 lv = latr[i];
      acc = fmaf(lv.x, w[4 * i + 0], acc);
      acc = fmaf(lv.y, w[4 * i + 1], acc);
      acc = fmaf(lv.z, w[4 * i + 2], acc);
      acc = fmaf(lv.w, w[4 * i + 3], acc);
    }
    float4 q = gp[(size_t)(u & 0xffffu) * 32 + cc];
    float t0 = q.w + acc;
    float z = (x - q.x) * q.y;
    float u0 = t0 + fmaf(-0.5f * z, z, q.z);
    float e1 = __expf(u0), e2 = __expf(t0);
    #pragma unroll
    for (int d = 1; d < 32; d <<= 1) {
      e1 += __shfl_xor(e1, d, 64);
      e2 += __shfl_xor(e2, d, 64);
    }
    if (cc == 0) lm += __logf(e1) - __logf(e2);
  }
  float bs = block_reduce(lm);
  if (threadIdx.x == 0) partials[blockIdx.x] = bs;
}

// ---------------- E: Poisson — block = 2 cells, counts in LDS ----------------
__global__ __launch_bounds__(TPB) void pois_v4(
    const unsigned* __restrict__ fpl, const unsigned* __restrict__ baseF,
    const float* __restrict__ latent, const int* __restrict__ genes_oi,
    const int* __restrict__ cells_oi,
    const float* __restrict__ rho_weight, const float* __restrict__ rho_bias,
    const float* __restrict__ libsize,
    float* __restrict__ partials, int N, int G) {
  int n0 = blockIdx.x * 2;
  __shared__ unsigned cnt[2 * MAXG];
  for (int t = threadIdx.x; t < 2 * MAXG; t += TPB) cnt[t] = 0;
  __shared__ __align__(16) float lat[128];
  for (int t = threadIdx.x; t < 128; t += TPB) {
    int j = t >> 6, l = t & 63;
    lat[t] = (n0 + j < N) ? latent[(size_t)(n0 + j) * 64 + l] : 0.f;
  }
  __syncthreads();
  int nhi = min(n0 + 2, N);
  unsigned s0 = baseF[n0], e0 = baseF[nhi];
  for (unsigned i = s0 + threadIdx.x; i < e0; i += TPB) {
    unsigned v = fpl[i];
    unsigned j = (v >> 16) - (unsigned)n0, g = v & 0xffffu;
    atomicAdd(&cnt[j * MAXG + g], 1u);
  }
  __syncthreads();
  float lib0 = (n0 < N) ? libsize[cells_oi[n0]] : 0.f;
  float lib1 = (n0 + 1 < N) ? libsize[cells_oi[n0 + 1]] : 0.f;
  float sum = 0.f;
  for (int g = threadIdx.x; g < G; g += TPB) {
    long long gene = genes_oi[g];
    const float4* rw = (const float4*)(rho_weight + gene * 64);
    float r0 = 0.f, r1 = 0.f;
    #pragma unroll
    for (int i = 0; i < 16; i++) {
      float4 wv = rw[i];
      float4 l0 = *(const float4*)(&lat[i * 4]);
      float4 l1 = *(const float4*)(&lat[64 + i * 4]);
      r0 = fmaf(wv.x, l0.x, r0); r0 = fmaf(wv.y, l0.y, r0);
      r0 = fmaf(wv.z, l0.z, r0); r0 = fmaf(wv.w, l0.w, r0);
      r1 = fmaf(wv.x, l1.x, r1); r1 = fmaf(wv.y, l1.y, r1);
      r1 = fmaf(wv.z, l1.z, r1); r1 = fmaf(wv.w, l1.w, r1);
    }
    float rb = rho_bias[gene];
    if (n0 < N) {
      float fe = rb * __expf(r0) * lib0;
      unsigned c = cnt[g];
      float term = -fe;
      if (c) {
        float lf = 0.f;
        for (unsigned q2 = 2; q2 <= c; q2++) lf += __logf((float)q2);
        term += (float)c * __logf(fe) - lf;
      }
      sum += term;
    }
    if (n0 + 1 < N) {
      float fe = rb * __expf(r1) * lib1;
      unsigned c = cnt[MAXG + g];
      float term = -fe;
      if (c) {
        float lf = 0.f;
        for (unsigned q2 = 2; q2 <= c; q2++) lf += __logf((float)q2);
        term += (float)c * __logf(fe) - lf;
      }
      sum += term;
    }
  }
  float bs = block_reduce(sum);
  if (threadIdx.x == 0) partials[blockIdx.x] = bs;
}

// ---------------- F: finalize ----------------
__global__ __launch_bounds__(TPB) void finalize_kernel(
    const float* __restrict__ p1, int n1,
    const float* __restrict__ p2, int n2, float* __restrict__ out) {
  float s = 0.f;
  for (int i = threadIdx.x; i < n1; i += TPB) s += p1[i];
  for (int i = threadIdx.x; i < n2; i += TPB) s += p2[i];
  float bs = block_reduce(s);
  if (threadIdx.x == 0) out[0] = -bs;
}

extern "C" void kernel_launch(void* const* d_in, const int* in_sizes, int n_in,
                              void* d_out, int out_size, void* d_ws, size_t ws_size,
                              hipStream_t stream) {
  const int*   lix          = (const int*)d_in[0];
  const float* xc           = (const float*)d_in[1];
  const float* latent       = (const float*)d_in[2];
  const int*   genes_oi     = (const int*)d_in[3];
  const int*   cells_oi     = (const int*)d_in[4];
  const int*   cxg          = (const int*)d_in[5];
  const int*   gix          = (const int*)d_in[6];
  const float* loc_w        = (const float*)d_in[9];
  const float* scale_w      = (const float*)d_in[10];
  const float* logit_w      = (const float*)d_in[11];
  const float* logit_weight = (const float*)d_in[12];
  const float* rho_weight   = (const float*)d_in[13];
  const float* rho_bias     = (const float*)d_in[14];
  const float* libsize      = (const float*)d_in[15];
  float* out = (float*)d_out;

  const int F = in_sizes[0];
  const int K = in_sizes[1];
  const int N = in_sizes[2] / 64;
  const int G = in_sizes[3];

  const int M = (K > F) ? K : F;
  const int B = (M + CHUNK - 1) / CHUNK;           // sort chunks
  const int PB = (N + 1) / 2;                      // pois blocks

  size_t off = 0;
  auto alloc = [&](size_t bytes) {
    size_t o = off;
    off = (off + bytes + 255) & ~(size_t)255;
    return o;
  };
  size_t cntC_off  = alloc((size_t)B * G * 4);
  size_t cntF_off  = alloc((size_t)B * N * 4);
  size_t totC_off  = alloc((size_t)G * 4);
  size_t totF_off  = alloc((size_t)N * 4);
  size_t baseC_off = alloc((size_t)(G + 1) * 4);
  size_t baseF_off = alloc((size_t)(N + 1) * 4);
  size_t pl_off    = alloc((size_t)K * 8);
  size_t fpl_off   = alloc((size_t)F * 4);
  size_t gp_off    = alloc((size_t)G * 32 * 16);
  size_t p1_off    = alloc((size_t)G * 4);
  size_t p2_off    = alloc((size_t)PB * 4);
  (void)ws_size;   // ~16 MB needed

  char* ws = (char*)d_ws;
  unsigned* cntC  = (unsigned*)(ws + cntC_off);
  unsigned* cntF  = (unsigned*)(ws + cntF_off);
  unsigned* totC  = (unsigned*)(ws + totC_off);
  unsigned* totF  = (unsigned*)(ws + totF_off);
  unsigned* baseC = (unsigned*)(ws + baseC_off);
  unsigned* baseF = (unsigned*)(ws + baseF_off);
  float2*   pl    = (float2*)(ws + pl_off);
  unsigned* fpl   = (unsigned*)(ws + fpl_off);
  float4*   gp    = (float4*)(ws + gp_off);
  float*    p1    = (float*)(ws + p1_off);
  float*    p2    = (float*)(ws + p2_off);

  gene_params_kernel<<<(G * 32 + TPB - 1) / TPB, TPB, 0, stream>>>(
      genes_oi, loc_w, scale_w, logit_w, gp, G);
  sort_pass1<<<B, TPB, 0, stream>>>(cxg, lix, cntC, cntF, K, F, (unsigned)G, (unsigned)N);
  colscan_kernel<<<(G + N + TPB - 1) / TPB, TPB, 0, stream>>>(
      cntC, cntF, totC, totF, B, (unsigned)G, (unsigned)N);
  scan2_kernel<<<1, TPB, 0, stream>>>(totC, baseC, G, (unsigned)K, totF, baseF, N, (unsigned)F);
  sort_pass3<<<B, TPB, 0, stream>>>(cxg, lix, xc, gix, cntC, cntF, baseC, baseF,
                                    pl, fpl, K, F, (unsigned)G, (unsigned)N);
  cuts_v4<<<G, TPB, 0, stream>>>(pl, latent, genes_oi, logit_weight, gp, baseC, p1, (unsigned)G);
  pois_v4<<<PB, TPB, 0, stream>>>(fpl, baseF, latent, genes_oi, cells_oi,
                                  rho_weight, rho_bias, libsize, p2, N, G);
  finalize_kernel<<<1, TPB, 0, stream>>>(p1, G, p2, PB, out);
}

// Round 5
// 793.102 us; speedup vs baseline: 1.0152x; 1.0152x over previous
//
#include <hip/hip_runtime.h>

// ELBO for the chromatin "Decoding" model — round 5.
// vs round 4:
//  * cuts_v5: w[64] VGPR residency FORCED via opaque asm pin (R3: compiler
//    demoted LDS-sourced w to in-loop ds_reads, VGPR=84; R4: demoted
//    global-sourced w to in-loop L1 streams, VGPR=52 -> 8KB L1/cut = 309us).
//    launch_bounds(256,3) for ~168 VGPR headroom.
//  * sort CHUNK 16384 -> 4096 (B: 62 -> 245 blocks). R4's 62-block sort was
//    latency-bound (~350us of the 496us non-cuts time).

#define TPB 256
#define CHUNK 4096
#define MAXG 4096
#define MAXN 1024
#define HALF_LOG_2PI 0.9189385332046727f

// 256-thread block reduction; valid in thread 0 only.
static __device__ __forceinline__ float block_reduce(float v) {
  #pragma unroll
  for (int off = 32; off > 0; off >>= 1) v += __shfl_down(v, off, 64);
  __shared__ float wsum[4];
  if ((threadIdx.x & 63) == 0) wsum[threadIdx.x >> 6] = v;
  __syncthreads();
  return (threadIdx.x == 0) ? (wsum[0] + wsum[1] + wsum[2] + wsum[3]) : 0.f;
}

// ---------------- A: gene params ----------------
__global__ __launch_bounds__(TPB) void gene_params_kernel(
    const int* __restrict__ genes_oi,
    const float* __restrict__ loc_w, const float* __restrict__ scale_w,
    const float* __restrict__ logit_w,
    float4* __restrict__ gp, int G) {
  int idx = blockIdx.x * TPB + threadIdx.x;       // over G*32
  if (idx >= G * 32) return;
  int g = idx >> 5, c = idx & 31;
  long long gene = genes_oi[g];
  float lv = loc_w[gene * 32 + c];
  float loc = 1.f / (1.f + __expf(-lv));
  float sc = 1e-5f + __expf(scale_w[gene * 32 + c]);
  gp[idx] = make_float4(loc, 1.f / sc, -__logf(sc) - HALF_LOG_2PI, logit_w[gene * 32 + c]);
}

// ---------------- S1: per-chunk LDS histograms (cuts by g_d, frags by n) ----
__global__ __launch_bounds__(TPB) void sort_pass1(
    const int* __restrict__ cxg, const int* __restrict__ lix,
    unsigned* __restrict__ cntC, unsigned* __restrict__ cntF,
    int K, int F, unsigned G, unsigned N) {
  __shared__ unsigned hC[MAXG];
  __shared__ unsigned hF[MAXN];
  for (int t = threadIdx.x; t < MAXG; t += TPB) hC[t] = 0;
  for (int t = threadIdx.x; t < MAXN; t += TPB) hF[t] = 0;
  __syncthreads();
  int i0 = blockIdx.x * CHUNK;
  for (int t = threadIdx.x; t < CHUNK; t += TPB) {
    int i = i0 + t;
    if (i < K) { unsigned ix = (unsigned)cxg[i]; atomicAdd(&hC[ix % G], 1u); }
    if (i < F) { unsigned v = (unsigned)lix[i]; atomicAdd(&hF[v / G], 1u); }
  }
  __syncthreads();
  size_t b = blockIdx.x;
  for (unsigned t = threadIdx.x; t < G; t += TPB) cntC[b * G + t] = hC[t];
  for (unsigned t = threadIdx.x; t < N; t += TPB) cntF[b * N + t] = hF[t];
}

// ---------------- S2a: per-bin column scan over chunks ----------------
__global__ __launch_bounds__(TPB) void colscan_kernel(
    unsigned* __restrict__ cntC, unsigned* __restrict__ cntF,
    unsigned* __restrict__ totC, unsigned* __restrict__ totF,
    int B, unsigned G, unsigned N) {
  unsigned t = blockIdx.x * TPB + threadIdx.x;
  if (t < G) {
    unsigned run = 0;
    for (int b = 0; b < B; b++) {
      unsigned v = cntC[(size_t)b * G + t];
      cntC[(size_t)b * G + t] = run;
      run += v;
    }
    totC[t] = run;
  } else if (t < G + N) {
    unsigned s = t - G;
    unsigned run = 0;
    for (int b = 0; b < B; b++) {
      unsigned v = cntF[(size_t)b * N + s];
      cntF[(size_t)b * N + s] = run;
      run += v;
    }
    totF[s] = run;
  }
}

// ---------------- S2b: single-block exclusive scans -> base offsets ---------
static __device__ void scan_dev(const unsigned* __restrict__ cnt,
                                unsigned* __restrict__ offs, int S, unsigned M) {
  __shared__ unsigned tmp[TPB];
  __shared__ unsigned base;
  if (threadIdx.x == 0) base = 0;
  __syncthreads();
  for (int c0 = 0; c0 < S; c0 += TPB) {
    int i = c0 + (int)threadIdx.x;
    unsigned v = (i < S) ? cnt[i] : 0u;
    tmp[threadIdx.x] = v;
    __syncthreads();
    for (int d = 1; d < TPB; d <<= 1) {
      unsigned t = (threadIdx.x >= (unsigned)d) ? tmp[threadIdx.x - d] : 0u;
      __syncthreads();
      tmp[threadIdx.x] += t;
      __syncthreads();
    }
    unsigned excl = tmp[threadIdx.x] - v + base;
    if (i < S) offs[i] = excl;
    __syncthreads();
    if (threadIdx.x == TPB - 1) base = excl + v;
    __syncthreads();
  }
  if (threadIdx.x == 0) offs[S] = M;
  __syncthreads();
}

__global__ __launch_bounds__(TPB) void scan2_kernel(
    const unsigned* __restrict__ totC, unsigned* __restrict__ baseC, int SC, unsigned K,
    const unsigned* __restrict__ totF, unsigned* __restrict__ baseF, int SF, unsigned F) {
  scan_dev(totC, baseC, SC, K);
  scan_dev(totF, baseF, SF, F);
}

// ---------------- S3: LDS-rank scatter (both sorts) ----------------
__global__ __launch_bounds__(TPB) void sort_pass3(
    const int* __restrict__ cxg, const int* __restrict__ lix,
    const float* __restrict__ xc, const int* __restrict__ gix,
    const unsigned* __restrict__ cntC, const unsigned* __restrict__ cntF,
    const unsigned* __restrict__ baseC, const unsigned* __restrict__ baseF,
    float2* __restrict__ pl, unsigned* __restrict__ fpl,
    int K, int F, unsigned G, unsigned N) {
  __shared__ unsigned cC[MAXG];
  __shared__ unsigned cF[MAXN];
  for (int t = threadIdx.x; t < MAXG; t += TPB) cC[t] = 0;
  for (int t = threadIdx.x; t < MAXN; t += TPB) cF[t] = 0;
  __syncthreads();
  int i0 = blockIdx.x * CHUNK;
  size_t b = blockIdx.x;
  for (int t = threadIdx.x; t < CHUNK; t += TPB) {
    int i = i0 + t;
    if (i < K) {
      unsigned ix = (unsigned)cxg[i];
      unsigned g = ix % G, n = ix / G;
      unsigned r = atomicAdd(&cC[g], 1u);
      unsigned pos = baseC[g] + cntC[b * G + g] + r;
      pl[pos] = make_float2(xc[i], __uint_as_float((n << 16) | (unsigned)gix[i]));
    }
    if (i < F) {
      unsigned v = (unsigned)lix[i];
      unsigned n = v / G, g = v - n * G;
      unsigned r = atomicAdd(&cF[n], 1u);
      fpl[baseF[n] + cntF[b * N + n] + r] = (n << 16) | g;
    }
  }
}

// ---------------- D: cuts v5 — 32-lane group/cut, weights PINNED in VGPRs ---
__global__ __launch_bounds__(TPB, 3) void cuts_v5(
    const float2* __restrict__ pl, const float* __restrict__ latent,
    const int* __restrict__ genes_oi, const float* __restrict__ logit_weight,
    const float4* __restrict__ gp, const unsigned* __restrict__ baseC,
    float* __restrict__ partials, unsigned G) {
  const int g = blockIdx.x;
  const int cc = threadIdx.x & 31;            // component (0..31)
  const int grp = (threadIdx.x >> 5) & 1;     // group within wave
  const int wv = threadIdx.x >> 6;

  // per-lane weight column from global, then PIN so the compiler cannot
  // rematerialize the loads inside the k-loop (R4: VGPR=52, 8KB L1/cut).
  const float* Wg = logit_weight + (size_t)genes_oi[g] * 2048 + cc;
  float w[64];
  #pragma unroll
  for (int l = 0; l < 64; l++) w[l] = Wg[l * 32];
  #pragma unroll
  for (int l = 0; l < 64; l++) asm volatile("" : "+v"(w[l]));

  const unsigned start = baseC[g], end = baseC[g + 1];
  float lm = 0.f;
  for (unsigned kk = start + wv * 2 + grp; kk < end; kk += 8) {
    float2 p = pl[kk];
    float x = p.x;
    unsigned u = __float_as_uint(p.y);
    const float4* latr = (const float4*)(latent + (size_t)(u >> 16) * 64);
    float acc = 0.f;
    #pragma unroll
    for (int i = 0; i < 16; i++) {
      float4 lv = latr[i];
      acc = fmaf(lv.x, w[4 * i + 0], acc);
      acc = fmaf(lv.y, w[4 * i + 1], acc);
      acc = fmaf(lv.z, w[4 * i + 2], acc);
      acc = fmaf(lv.w, w[4 * i + 3], acc);
    }
    float4 q = gp[(size_t)(u & 0xffffu) * 32 + cc];
    float t0 = q.w + acc;
    float z = (x - q.x) * q.y;
    float u0 = t0 + fmaf(-0.5f * z, z, q.z);
    float e1 = __expf(u0), e2 = __expf(t0);
    #pragma unroll
    for (int d = 1; d < 32; d <<= 1) {
      e1 += __shfl_xor(e1, d, 64);
      e2 += __shfl_xor(e2, d, 64);
    }
    if (cc == 0) lm += __logf(e1) - __logf(e2);
  }
  float bs = block_reduce(lm);
  if (threadIdx.x == 0) partials[blockIdx.x] = bs;
}

// ---------------- E: Poisson — block = 2 cells, counts in LDS ----------------
__global__ __launch_bounds__(TPB) void pois_v4(
    const unsigned* __restrict__ fpl, const unsigned* __restrict__ baseF,
    const float* __restrict__ latent, const int* __restrict__ genes_oi,
    const int* __restrict__ cells_oi,
    const float* __restrict__ rho_weight, const float* __restrict__ rho_bias,
    const float* __restrict__ libsize,
    float* __restrict__ partials, int N, int G) {
  int n0 = blockIdx.x * 2;
  __shared__ unsigned cnt[2 * MAXG];
  for (int t = threadIdx.x; t < 2 * MAXG; t += TPB) cnt[t] = 0;
  __shared__ __align__(16) float lat[128];
  for (int t = threadIdx.x; t < 128; t += TPB) {
    int j = t >> 6, l = t & 63;
    lat[t] = (n0 + j < N) ? latent[(size_t)(n0 + j) * 64 + l] : 0.f;
  }
  __syncthreads();
  int nhi = min(n0 + 2, N);
  unsigned s0 = baseF[n0], e0 = baseF[nhi];
  for (unsigned i = s0 + threadIdx.x; i < e0; i += TPB) {
    unsigned v = fpl[i];
    unsigned j = (v >> 16) - (unsigned)n0, g = v & 0xffffu;
    atomicAdd(&cnt[j * MAXG + g], 1u);
  }
  __syncthreads();
  float lib0 = (n0 < N) ? libsize[cells_oi[n0]] : 0.f;
  float lib1 = (n0 + 1 < N) ? libsize[cells_oi[n0 + 1]] : 0.f;
  float sum = 0.f;
  for (int g = threadIdx.x; g < G; g += TPB) {
    long long gene = genes_oi[g];
    const float4* rw = (const float4*)(rho_weight + gene * 64);
    float r0 = 0.f, r1 = 0.f;
    #pragma unroll
    for (int i = 0; i < 16; i++) {
      float4 wv = rw[i];
      float4 l0 = *(const float4*)(&lat[i * 4]);
      float4 l1 = *(const float4*)(&lat[64 + i * 4]);
      r0 = fmaf(wv.x, l0.x, r0); r0 = fmaf(wv.y, l0.y, r0);
      r0 = fmaf(wv.z, l0.z, r0); r0 = fmaf(wv.w, l0.w, r0);
      r1 = fmaf(wv.x, l1.x, r1); r1 = fmaf(wv.y, l1.y, r1);
      r1 = fmaf(wv.z, l1.z, r1); r1 = fmaf(wv.w, l1.w, r1);
    }
    float rb = rho_bias[gene];
    if (n0 < N) {
      float fe = rb * __expf(r0) * lib0;
      unsigned c = cnt[g];
      float term = -fe;
      if (c) {
        float lf = 0.f;
        for (unsigned q2 = 2; q2 <= c; q2++) lf += __logf((float)q2);
        term += (float)c * __logf(fe) - lf;
      }
      sum += term;
    }
    if (n0 + 1 < N) {
      float fe = rb * __expf(r1) * lib1;
      unsigned c = cnt[MAXG + g];
      float term = -fe;
      if (c) {
        float lf = 0.f;
        for (unsigned q2 = 2; q2 <= c; q2++) lf += __logf((float)q2);
        term += (float)c * __logf(fe) - lf;
      }
      sum += term;
    }
  }
  float bs = block_reduce(sum);
  if (threadIdx.x == 0) partials[blockIdx.x] = bs;
}

// ---------------- F: finalize ----------------
__global__ __launch_bounds__(TPB) void finalize_kernel(
    const float* __restrict__ p1, int n1,
    const float* __restrict__ p2, int n2, float* __restrict__ out) {
  float s = 0.f;
  for (int i = threadIdx.x; i < n1; i += TPB) s += p1[i];
  for (int i = threadIdx.x; i < n2; i += TPB) s += p2[i];
  float bs = block_reduce(s);
  if (threadIdx.x == 0) out[0] = -bs;
}

extern "C" void kernel_launch(void* const* d_in, const int* in_sizes, int n_in,
                              void* d_out, int out_size, void* d_ws, size_t ws_size,
                              hipStream_t stream) {
  const int*   lix          = (const int*)d_in[0];
  const float* xc           = (const float*)d_in[1];
  const float* latent       = (const float*)d_in[2];
  const int*   genes_oi     = (const int*)d_in[3];
  const int*   cells_oi     = (const int*)d_in[4];
  const int*   cxg          = (const int*)d_in[5];
  const int*   gix          = (const int*)d_in[6];
  const float* loc_w        = (const float*)d_in[9];
  const float* scale_w      = (const float*)d_in[10];
  const float* logit_w      = (const float*)d_in[11];
  const float* logit_weight = (const float*)d_in[12];
  const float* rho_weight   = (const float*)d_in[13];
  const float* rho_bias     = (const float*)d_in[14];
  const float* libsize      = (const float*)d_in[15];
  float* out = (float*)d_out;

  const int F = in_sizes[0];
  const int K = in_sizes[1];
  const int N = in_sizes[2] / 64;
  const int G = in_sizes[3];

  const int M = (K > F) ? K : F;
  const int B = (M + CHUNK - 1) / CHUNK;           // sort chunks
  const int PB = (N + 1) / 2;                      // pois blocks

  size_t off = 0;
  auto alloc = [&](size_t bytes) {
    size_t o = off;
    off = (off + bytes + 255) & ~(size_t)255;
    return o;
  };
  size_t cntC_off  = alloc((size_t)B * G * 4);
  size_t cntF_off  = alloc((size_t)B * N * 4);
  size_t totC_off  = alloc((size_t)G * 4);
  size_t totF_off  = alloc((size_t)N * 4);
  size_t baseC_off = alloc((size_t)(G + 1) * 4);
  size_t baseF_off = alloc((size_t)(N + 1) * 4);
  size_t pl_off    = alloc((size_t)K * 8);
  size_t fpl_off   = alloc((size_t)F * 4);
  size_t gp_off    = alloc((size_t)G * 32 * 16);
  size_t p1_off    = alloc((size_t)G * 4);
  size_t p2_off    = alloc((size_t)PB * 4);
  (void)ws_size;   // ~22 MB needed

  char* ws = (char*)d_ws;
  unsigned* cntC  = (unsigned*)(ws + cntC_off);
  unsigned* cntF  = (unsigned*)(ws + cntF_off);
  unsigned* totC  = (unsigned*)(ws + totC_off);
  unsigned* totF  = (unsigned*)(ws + totF_off);
  unsigned* baseC = (unsigned*)(ws + baseC_off);
  unsigned* baseF = (unsigned*)(ws + baseF_off);
  float2*   pl    = (float2*)(ws + pl_off);
  unsigned* fpl   = (unsigned*)(ws + fpl_off);
  float4*   gp    = (float4*)(ws + gp_off);
  float*    p1    = (float*)(ws + p1_off);
  float*    p2    = (float*)(ws + p2_off);

  gene_params_kernel<<<(G * 32 + TPB - 1) / TPB, TPB, 0, stream>>>(
      genes_oi, loc_w, scale_w, logit_w, gp, G);
  sort_pass1<<<B, TPB, 0, stream>>>(cxg, lix, cntC, cntF, K, F, (unsigned)G, (unsigned)N);
  colscan_kernel<<<(G + N + TPB - 1) / TPB, TPB, 0, stream>>>(
      cntC, cntF, totC, totF, B, (unsigned)G, (unsigned)N);
  scan2_kernel<<<1, TPB, 0, stream>>>(totC, baseC, G, (unsigned)K, totF, baseF, N, (unsigned)F);
  sort_pass3<<<B, TPB, 0, stream>>>(cxg, lix, xc, gix, cntC, cntF, baseC, baseF,
                                    pl, fpl, K, F, (unsigned)G, (unsigned)N);
  cuts_v5<<<G, TPB, 0, stream>>>(pl, latent, genes_oi, logit_weight, gp, baseC, p1, (unsigned)G);
  pois_v4<<<PB, TPB, 0, stream>>>(fpl, baseF, latent, genes_oi, cells_oi,
                                  rho_weight, rho_bias, libsize, p2, N, G);
  finalize_kernel<<<1, TPB, 0, stream>>>(p1, G, p2, PB, out);
}

// Round 6
// 533.575 us; speedup vs baseline: 1.5090x; 1.4864x over previous
//
#include <hip/hip_runtime.h>

// ELBO for the chromatin "Decoding" model — round 6.
// vs round 5: cuts kernel moved to MFMA. R3/R4/R5 proved the scalar register
// allocator will not keep a per-lane 64-float weight array live (VGPR counts
// 84/52/48 = LDS-remat / L1-remat / scratch-spill). MFMA B-operands are the
// one structurally register-resident form: per gene, W[64x32] lives in 4
// bf16x8 fragments (16 VGPRs); a wave computes a 16-cut x 32-comp delta tile
// with 4 v_mfma_f32_16x16x32_bf16. Latent is pre-converted to bf16 so A-frags
// are single 16B loads. Sort/poisson/scan unchanged from R5.

#define TPB 256
#define CHUNK 4096
#define MAXG 4096
#define MAXN 1024
#define HALF_LOG_2PI 0.9189385332046727f

typedef short bf16x8 __attribute__((ext_vector_type(8)));
typedef float f32x4 __attribute__((ext_vector_type(4)));

static __device__ __forceinline__ unsigned short f2bf(float f) {
  unsigned u = __float_as_uint(f);
  u += 0x7fffu + ((u >> 16) & 1u);   // RNE
  return (unsigned short)(u >> 16);
}

// 256-thread block reduction; valid in thread 0 only.
static __device__ __forceinline__ float block_reduce(float v) {
  #pragma unroll
  for (int off = 32; off > 0; off >>= 1) v += __shfl_down(v, off, 64);
  __shared__ float wsum[4];
  if ((threadIdx.x & 63) == 0) wsum[threadIdx.x >> 6] = v;
  __syncthreads();
  return (threadIdx.x == 0) ? (wsum[0] + wsum[1] + wsum[2] + wsum[3]) : 0.f;
}

// ---------------- A: gene params + latent->bf16 prep ----------------
__global__ __launch_bounds__(TPB) void gene_params_kernel(
    const int* __restrict__ genes_oi,
    const float* __restrict__ loc_w, const float* __restrict__ scale_w,
    const float* __restrict__ logit_w,
    const float* __restrict__ latent,
    float4* __restrict__ gp, unsigned short* __restrict__ latbf,
    int G, int NL) {
  int idx = blockIdx.x * TPB + threadIdx.x;
  int ngp = G * 32;
  if (idx < ngp) {
    int g = idx >> 5, c = idx & 31;
    long long gene = genes_oi[g];
    float lv = loc_w[gene * 32 + c];
    float loc = 1.f / (1.f + __expf(-lv));
    float sc = 1e-5f + __expf(scale_w[gene * 32 + c]);
    gp[idx] = make_float4(loc, 1.f / sc, -__logf(sc) - HALF_LOG_2PI, logit_w[gene * 32 + c]);
  } else {
    int t = idx - ngp;
    if (t < NL) latbf[t] = f2bf(latent[t]);
  }
}

// ---------------- S1: per-chunk LDS histograms (cuts by g_d, frags by n) ----
__global__ __launch_bounds__(TPB) void sort_pass1(
    const int* __restrict__ cxg, const int* __restrict__ lix,
    unsigned* __restrict__ cntC, unsigned* __restrict__ cntF,
    int K, int F, unsigned G, unsigned N) {
  __shared__ unsigned hC[MAXG];
  __shared__ unsigned hF[MAXN];
  for (int t = threadIdx.x; t < MAXG; t += TPB) hC[t] = 0;
  for (int t = threadIdx.x; t < MAXN; t += TPB) hF[t] = 0;
  __syncthreads();
  int i0 = blockIdx.x * CHUNK;
  for (int t = threadIdx.x; t < CHUNK; t += TPB) {
    int i = i0 + t;
    if (i < K) { unsigned ix = (unsigned)cxg[i]; atomicAdd(&hC[ix % G], 1u); }
    if (i < F) { unsigned v = (unsigned)lix[i]; atomicAdd(&hF[v / G], 1u); }
  }
  __syncthreads();
  size_t b = blockIdx.x;
  for (unsigned t = threadIdx.x; t < G; t += TPB) cntC[b * G + t] = hC[t];
  for (unsigned t = threadIdx.x; t < N; t += TPB) cntF[b * N + t] = hF[t];
}

// ---------------- S2a: per-bin column scan over chunks ----------------
__global__ __launch_bounds__(TPB) void colscan_kernel(
    unsigned* __restrict__ cntC, unsigned* __restrict__ cntF,
    unsigned* __restrict__ totC, unsigned* __restrict__ totF,
    int B, unsigned G, unsigned N) {
  unsigned t = blockIdx.x * TPB + threadIdx.x;
  if (t < G) {
    unsigned run = 0;
    for (int b = 0; b < B; b++) {
      unsigned v = cntC[(size_t)b * G + t];
      cntC[(size_t)b * G + t] = run;
      run += v;
    }
    totC[t] = run;
  } else if (t < G + N) {
    unsigned s = t - G;
    unsigned run = 0;
    for (int b = 0; b < B; b++) {
      unsigned v = cntF[(size_t)b * N + s];
      cntF[(size_t)b * N + s] = run;
      run += v;
    }
    totF[s] = run;
  }
}

// ---------------- S2b: single-block exclusive scans -> base offsets ---------
static __device__ void scan_dev(const unsigned* __restrict__ cnt,
                                unsigned* __restrict__ offs, int S, unsigned M) {
  __shared__ unsigned tmp[TPB];
  __shared__ unsigned base;
  if (threadIdx.x == 0) base = 0;
  __syncthreads();
  for (int c0 = 0; c0 < S; c0 += TPB) {
    int i = c0 + (int)threadIdx.x;
    unsigned v = (i < S) ? cnt[i] : 0u;
    tmp[threadIdx.x] = v;
    __syncthreads();
    for (int d = 1; d < TPB; d <<= 1) {
      unsigned t = (threadIdx.x >= (unsigned)d) ? tmp[threadIdx.x - d] : 0u;
      __syncthreads();
      tmp[threadIdx.x] += t;
      __syncthreads();
    }
    unsigned excl = tmp[threadIdx.x] - v + base;
    if (i < S) offs[i] = excl;
    __syncthreads();
    if (threadIdx.x == TPB - 1) base = excl + v;
    __syncthreads();
  }
  if (threadIdx.x == 0) offs[S] = M;
  __syncthreads();
}

__global__ __launch_bounds__(TPB) void scan2_kernel(
    const unsigned* __restrict__ totC, unsigned* __restrict__ baseC, int SC, unsigned K,
    const unsigned* __restrict__ totF, unsigned* __restrict__ baseF, int SF, unsigned F) {
  scan_dev(totC, baseC, SC, K);
  scan_dev(totF, baseF, SF, F);
}

// ---------------- S3: LDS-rank scatter (both sorts) ----------------
__global__ __launch_bounds__(TPB) void sort_pass3(
    const int* __restrict__ cxg, const int* __restrict__ lix,
    const float* __restrict__ xc, const int* __restrict__ gix,
    const unsigned* __restrict__ cntC, const unsigned* __restrict__ cntF,
    const unsigned* __restrict__ baseC, const unsigned* __restrict__ baseF,
    float2* __restrict__ pl, unsigned* __restrict__ fpl,
    int K, int F, unsigned G, unsigned N) {
  __shared__ unsigned cC[MAXG];
  __shared__ unsigned cF[MAXN];
  for (int t = threadIdx.x; t < MAXG; t += TPB) cC[t] = 0;
  for (int t = threadIdx.x; t < MAXN; t += TPB) cF[t] = 0;
  __syncthreads();
  int i0 = blockIdx.x * CHUNK;
  size_t b = blockIdx.x;
  for (int t = threadIdx.x; t < CHUNK; t += TPB) {
    int i = i0 + t;
    if (i < K) {
      unsigned ix = (unsigned)cxg[i];
      unsigned g = ix % G, n = ix / G;
      unsigned r = atomicAdd(&cC[g], 1u);
      unsigned pos = baseC[g] + cntC[b * G + g] + r;
      pl[pos] = make_float2(xc[i], __uint_as_float((n << 16) | (unsigned)gix[i]));
    }
    if (i < F) {
      unsigned v = (unsigned)lix[i];
      unsigned n = v / G, g = v - n * G;
      unsigned r = atomicAdd(&cF[n], 1u);
      fpl[baseF[n] + cntF[b * N + n] + r] = (n << 16) | g;
    }
  }
}

// ---------------- D: cuts v6 — MFMA 16x16x32 bf16 ----------------
// Block per gene, 4 waves. Wave tile = 16 cuts x 32 comps:
//   delta = latbf[cuts x 64] @ W[64 x 32]  via 4 mfma (K split 2, N split 2).
// A-frag: lane m=lane&15 (cut), k=quad*8+j -> contiguous 16B bf16 load.
// B-frag: lane n=lane&15 (comp), k=quad*8+j -> 8 strided fp32, cvt once/gene.
// D: col(comp)=lane&15, row(cut)=quad*4+reg.
__global__ __launch_bounds__(TPB) void cuts_v6(
    const float2* __restrict__ pl, const unsigned short* __restrict__ latbf,
    const int* __restrict__ genes_oi, const float* __restrict__ logit_weight,
    const float4* __restrict__ gp, const unsigned* __restrict__ baseC,
    float* __restrict__ partials, unsigned G) {
  const int g = blockIdx.x;
  const int lane = threadIdx.x & 63;
  const int wv = threadIdx.x >> 6;
  const int quad = lane >> 4;
  const int r16 = lane & 15;

  // B fragments (weights) — once per gene, register-resident as MFMA operands
  const float* Wb = logit_weight + (size_t)genes_oi[g] * 2048;
  bf16x8 B0a, B1a, B0b, B1b;
  #pragma unroll
  for (int j = 0; j < 8; j++) {
    int l0 = quad * 8 + j;
    B0a[j] = (short)f2bf(Wb[l0 * 32 + r16]);
    B1a[j] = (short)f2bf(Wb[(l0 + 32) * 32 + r16]);
    B0b[j] = (short)f2bf(Wb[l0 * 32 + r16 + 16]);
    B1b[j] = (short)f2bf(Wb[(l0 + 32) * 32 + r16 + 16]);
  }

  const unsigned start = baseC[g], end = baseC[g + 1];
  const unsigned ntiles = (end - start + 15) >> 4;
  float lm = 0.f;

  for (unsigned t = wv; t < ntiles; t += 4) {
    unsigned kk0 = start + t * 16;
    unsigned idx = kk0 + r16;
    float2 p = pl[idx < end ? idx : start];
    unsigned u = __float_as_uint(p.y);
    const unsigned short* lb = latbf + (size_t)(u >> 16) * 64;
    bf16x8 A0 = *(const bf16x8*)(lb + quad * 8);
    bf16x8 A1 = *(const bf16x8*)(lb + 32 + quad * 8);

    f32x4 acc0 = {0.f, 0.f, 0.f, 0.f};
    f32x4 acc1 = {0.f, 0.f, 0.f, 0.f};
    acc0 = __builtin_amdgcn_mfma_f32_16x16x32_bf16(A0, B0a, acc0, 0, 0, 0);
    acc0 = __builtin_amdgcn_mfma_f32_16x16x32_bf16(A1, B1a, acc0, 0, 0, 0);
    acc1 = __builtin_amdgcn_mfma_f32_16x16x32_bf16(A0, B0b, acc1, 0, 0, 0);
    acc1 = __builtin_amdgcn_mfma_f32_16x16x32_bf16(A1, B1b, acc1, 0, 0, 0);

    #pragma unroll
    for (int r = 0; r < 4; r++) {
      int cut = quad * 4 + r;
      float xr = __shfl(p.x, cut, 64);
      unsigned ur = (unsigned)__shfl((int)u, cut, 64);
      unsigned gi = ur & 0xffffu;
      float4 q0 = gp[(size_t)gi * 32 + r16];
      float4 q1 = gp[(size_t)gi * 32 + r16 + 16];
      float t0 = q0.w + acc0[r], t1 = q1.w + acc1[r];
      float z0 = (xr - q0.x) * q0.y, z1 = (xr - q1.x) * q1.y;
      float u0 = t0 + fmaf(-0.5f * z0, z0, q0.z);
      float u1 = t1 + fmaf(-0.5f * z1, z1, q1.z);
      float e1 = __expf(u0) + __expf(u1);
      float e2 = __expf(t0) + __expf(t1);
      #pragma unroll
      for (int d = 1; d < 16; d <<= 1) {
        e1 += __shfl_xor(e1, d, 64);
        e2 += __shfl_xor(e2, d, 64);
      }
      if (r16 == 0 && (kk0 + (unsigned)cut) < end) lm += __logf(e1) - __logf(e2);
    }
  }
  float bs = block_reduce(lm);
  if (threadIdx.x == 0) partials[blockIdx.x] = bs;
}

// ---------------- E: Poisson — block = 2 cells, counts in LDS ----------------
__global__ __launch_bounds__(TPB) void pois_v4(
    const unsigned* __restrict__ fpl, const unsigned* __restrict__ baseF,
    const float* __restrict__ latent, const int* __restrict__ genes_oi,
    const int* __restrict__ cells_oi,
    const float* __restrict__ rho_weight, const float* __restrict__ rho_bias,
    const float* __restrict__ libsize,
    float* __restrict__ partials, int N, int G) {
  int n0 = blockIdx.x * 2;
  __shared__ unsigned cnt[2 * MAXG];
  for (int t = threadIdx.x; t < 2 * MAXG; t += TPB) cnt[t] = 0;
  __shared__ __align__(16) float lat[128];
  for (int t = threadIdx.x; t < 128; t += TPB) {
    int j = t >> 6, l = t & 63;
    lat[t] = (n0 + j < N) ? latent[(size_t)(n0 + j) * 64 + l] : 0.f;
  }
  __syncthreads();
  int nhi = min(n0 + 2, N);
  unsigned s0 = baseF[n0], e0 = baseF[nhi];
  for (unsigned i = s0 + threadIdx.x; i < e0; i += TPB) {
    unsigned v = fpl[i];
    unsigned j = (v >> 16) - (unsigned)n0, g = v & 0xffffu;
    atomicAdd(&cnt[j * MAXG + g], 1u);
  }
  __syncthreads();
  float lib0 = (n0 < N) ? libsize[cells_oi[n0]] : 0.f;
  float lib1 = (n0 + 1 < N) ? libsize[cells_oi[n0 + 1]] : 0.f;
  float sum = 0.f;
  for (int g = threadIdx.x; g < G; g += TPB) {
    long long gene = genes_oi[g];
    const float4* rw = (const float4*)(rho_weight + gene * 64);
    float r0 = 0.f, r1 = 0.f;
    #pragma unroll
    for (int i = 0; i < 16; i++) {
      float4 wv = rw[i];
      float4 l0 = *(const float4*)(&lat[i * 4]);
      float4 l1 = *(const float4*)(&lat[64 + i * 4]);
      r0 = fmaf(wv.x, l0.x, r0); r0 = fmaf(wv.y, l0.y, r0);
      r0 = fmaf(wv.z, l0.z, r0); r0 = fmaf(wv.w, l0.w, r0);
      r1 = fmaf(wv.x, l1.x, r1); r1 = fmaf(wv.y, l1.y, r1);
      r1 = fmaf(wv.z, l1.z, r1); r1 = fmaf(wv.w, l1.w, r1);
    }
    float rb = rho_bias[gene];
    if (n0 < N) {
      float fe = rb * __expf(r0) * lib0;
      unsigned c = cnt[g];
      float term = -fe;
      if (c) {
        float lf = 0.f;
        for (unsigned q2 = 2; q2 <= c; q2++) lf += __logf((float)q2);
        term += (float)c * __logf(fe) - lf;
      }
      sum += term;
    }
    if (n0 + 1 < N) {
      float fe = rb * __expf(r1) * lib1;
      unsigned c = cnt[MAXG + g];
      float term = -fe;
      if (c) {
        float lf = 0.f;
        for (unsigned q2 = 2; q2 <= c; q2++) lf += __logf((float)q2);
        term += (float)c * __logf(fe) - lf;
      }
      sum += term;
    }
  }
  float bs = block_reduce(sum);
  if (threadIdx.x == 0) partials[blockIdx.x] = bs;
}

// ---------------- F: finalize ----------------
__global__ __launch_bounds__(TPB) void finalize_kernel(
    const float* __restrict__ p1, int n1,
    const float* __restrict__ p2, int n2, float* __restrict__ out) {
  float s = 0.f;
  for (int i = threadIdx.x; i < n1; i += TPB) s += p1[i];
  for (int i = threadIdx.x; i < n2; i += TPB) s += p2[i];
  float bs = block_reduce(s);
  if (threadIdx.x == 0) out[0] = -bs;
}

extern "C" void kernel_launch(void* const* d_in, const int* in_sizes, int n_in,
                              void* d_out, int out_size, void* d_ws, size_t ws_size,
                              hipStream_t stream) {
  const int*   lix          = (const int*)d_in[0];
  const float* xc           = (const float*)d_in[1];
  const float* latent       = (const float*)d_in[2];
  const int*   genes_oi     = (const int*)d_in[3];
  const int*   cells_oi     = (const int*)d_in[4];
  const int*   cxg          = (const int*)d_in[5];
  const int*   gix          = (const int*)d_in[6];
  const float* loc_w        = (const float*)d_in[9];
  const float* scale_w      = (const float*)d_in[10];
  const float* logit_w      = (const float*)d_in[11];
  const float* logit_weight = (const float*)d_in[12];
  const float* rho_weight   = (const float*)d_in[13];
  const float* rho_bias     = (const float*)d_in[14];
  const float* libsize      = (const float*)d_in[15];
  float* out = (float*)d_out;

  const int F = in_sizes[0];
  const int K = in_sizes[1];
  const int N = in_sizes[2] / 64;
  const int G = in_sizes[3];
  const int NL = N * 64;

  const int M = (K > F) ? K : F;
  const int B = (M + CHUNK - 1) / CHUNK;           // sort chunks
  const int PB = (N + 1) / 2;                      // pois blocks

  size_t off = 0;
  auto alloc = [&](size_t bytes) {
    size_t o = off;
    off = (off + bytes + 255) & ~(size_t)255;
    return o;
  };
  size_t cntC_off  = alloc((size_t)B * G * 4);
  size_t cntF_off  = alloc((size_t)B * N * 4);
  size_t totC_off  = alloc((size_t)G * 4);
  size_t totF_off  = alloc((size_t)N * 4);
  size_t baseC_off = alloc((size_t)(G + 1) * 4);
  size_t baseF_off = alloc((size_t)(N + 1) * 4);
  size_t pl_off    = alloc((size_t)K * 8);
  size_t fpl_off   = alloc((size_t)F * 4);
  size_t gp_off    = alloc((size_t)G * 32 * 16);
  size_t lb_off    = alloc((size_t)NL * 2);
  size_t p1_off    = alloc((size_t)G * 4);
  size_t p2_off    = alloc((size_t)PB * 4);
  (void)ws_size;   // ~22 MB needed

  char* ws = (char*)d_ws;
  unsigned* cntC  = (unsigned*)(ws + cntC_off);
  unsigned* cntF  = (unsigned*)(ws + cntF_off);
  unsigned* totC  = (unsigned*)(ws + totC_off);
  unsigned* totF  = (unsigned*)(ws + totF_off);
  unsigned* baseC = (unsigned*)(ws + baseC_off);
  unsigned* baseF = (unsigned*)(ws + baseF_off);
  float2*   pl    = (float2*)(ws + pl_off);
  unsigned* fpl   = (unsigned*)(ws + fpl_off);
  float4*   gp    = (float4*)(ws + gp_off);
  unsigned short* latbf = (unsigned short*)(ws + lb_off);
  float*    p1    = (float*)(ws + p1_off);
  float*    p2    = (float*)(ws + p2_off);

  gene_params_kernel<<<(G * 32 + NL + TPB - 1) / TPB, TPB, 0, stream>>>(
      genes_oi, loc_w, scale_w, logit_w, latent, gp, latbf, G, NL);
  sort_pass1<<<B, TPB, 0, stream>>>(cxg, lix, cntC, cntF, K, F, (unsigned)G, (unsigned)N);
  colscan_kernel<<<(G + N + TPB - 1) / TPB, TPB, 0, stream>>>(
      cntC, cntF, totC, totF, B, (unsigned)G, (unsigned)N);
  scan2_kernel<<<1, TPB, 0, stream>>>(totC, baseC, G, (unsigned)K, totF, baseF, N, (unsigned)F);
  sort_pass3<<<B, TPB, 0, stream>>>(cxg, lix, xc, gix, cntC, cntF, baseC, baseF,
                                    pl, fpl, K, F, (unsigned)G, (unsigned)N);
  cuts_v6<<<G, TPB, 0, stream>>>(pl, latbf, genes_oi, logit_weight, gp, baseC, p1, (unsigned)G);
  pois_v4<<<PB, TPB, 0, stream>>>(fpl, baseF, latent, genes_oi, cells_oi,
                                  rho_weight, rho_bias, libsize, p2, N, G);
  finalize_kernel<<<1, TPB, 0, stream>>>(p1, G, p2, PB, out);
}

// Round 7
// 447.762 us; speedup vs baseline: 1.7982x; 1.1916x over previous
//
#include <hip/hip_runtime.h>

// ELBO for the chromatin "Decoding" model — round 7.
// vs round 6:
//  * colscan_v2: one WAVE per bin (R6: one thread per bin walked 245 strided
//    loads serially -> 114us at 0.4% occupancy). Shuffle prefix scan.
//  * scan2_v2: two independent single-wave shuffle scans, zero barriers
//    (old version: ~290 __syncthreads on one block).
//  * gene_params fused into the hist launch; finalize fused into pois via
//    last-block ticket. 9 -> 6 dispatches.

#define TPB 256
#define CHUNK 4096
#define MAXG 4096
#define MAXN 1024
#define HALF_LOG_2PI 0.9189385332046727f

typedef short bf16x8 __attribute__((ext_vector_type(8)));
typedef float f32x4 __attribute__((ext_vector_type(4)));

static __device__ __forceinline__ unsigned short f2bf(float f) {
  unsigned u = __float_as_uint(f);
  u += 0x7fffu + ((u >> 16) & 1u);   // RNE
  return (unsigned short)(u >> 16);
}

// 256-thread block reduction; valid in thread 0 only.
static __device__ __forceinline__ float block_reduce(float v) {
  #pragma unroll
  for (int off = 32; off > 0; off >>= 1) v += __shfl_down(v, off, 64);
  __shared__ float wsum[4];
  if ((threadIdx.x & 63) == 0) wsum[threadIdx.x >> 6] = v;
  __syncthreads();
  return (threadIdx.x == 0) ? (wsum[0] + wsum[1] + wsum[2] + wsum[3]) : 0.f;
}

// ---------------- P1: fused per-chunk histograms + gene params + latbf -----
__global__ __launch_bounds__(TPB) void prep_hist_kernel(
    const int* __restrict__ cxg, const int* __restrict__ lix,
    unsigned* __restrict__ cntC, unsigned* __restrict__ cntF,
    const int* __restrict__ genes_oi,
    const float* __restrict__ loc_w, const float* __restrict__ scale_w,
    const float* __restrict__ logit_w, const float* __restrict__ latent,
    float4* __restrict__ gp, unsigned short* __restrict__ latbf,
    int K, int F, unsigned G, unsigned N, int B, int NL) {
  if ((int)blockIdx.x >= B) {
    // gene params + latent->bf16
    int idx = ((int)blockIdx.x - B) * TPB + threadIdx.x;
    int ngp = (int)G * 32;
    if (idx < ngp) {
      int g = idx >> 5, c = idx & 31;
      long long gene = genes_oi[g];
      float lv = loc_w[gene * 32 + c];
      float loc = 1.f / (1.f + __expf(-lv));
      float sc = 1e-5f + __expf(scale_w[gene * 32 + c]);
      gp[idx] = make_float4(loc, 1.f / sc, -__logf(sc) - HALF_LOG_2PI, logit_w[gene * 32 + c]);
    } else if (idx - ngp < NL) {
      latbf[idx - ngp] = f2bf(latent[idx - ngp]);
    }
    return;
  }
  __shared__ unsigned hC[MAXG];
  __shared__ unsigned hF[MAXN];
  for (int t = threadIdx.x; t < MAXG; t += TPB) hC[t] = 0;
  for (int t = threadIdx.x; t < MAXN; t += TPB) hF[t] = 0;
  __syncthreads();
  int i0 = blockIdx.x * CHUNK;
  for (int t = threadIdx.x; t < CHUNK; t += TPB) {
    int i = i0 + t;
    if (i < K) { unsigned ix = (unsigned)cxg[i]; atomicAdd(&hC[ix % G], 1u); }
    if (i < F) { unsigned v = (unsigned)lix[i]; atomicAdd(&hF[v / G], 1u); }
  }
  __syncthreads();
  size_t b = blockIdx.x;
  for (unsigned t = threadIdx.x; t < G; t += TPB) cntC[b * G + t] = hC[t];
  for (unsigned t = threadIdx.x; t < N; t += TPB) cntF[b * N + t] = hF[t];
}

// ---------------- S2a: column scan, one wave per bin ----------------
__global__ __launch_bounds__(TPB) void colscan_v2(
    unsigned* __restrict__ cntC, unsigned* __restrict__ cntF,
    unsigned* __restrict__ totC, unsigned* __restrict__ totF,
    int B, unsigned G, unsigned N) {
  unsigned wid = blockIdx.x * 4 + (threadIdx.x >> 6);
  int lane = threadIdx.x & 63;
  if (wid >= G + N) return;
  unsigned* col;
  unsigned stride;
  unsigned* tot;
  if (wid < G) { col = cntC + wid; stride = G; tot = totC + wid; }
  else         { col = cntF + (wid - G); stride = N; tot = totF + (wid - G); }
  unsigned base = 0;
  for (int b0 = 0; b0 < B; b0 += 64) {
    int b = b0 + lane;
    unsigned v = (b < B) ? col[(size_t)b * stride] : 0u;
    unsigned inc = v;
    #pragma unroll
    for (int d = 1; d < 64; d <<= 1) {
      unsigned t2 = __shfl_up(inc, d, 64);
      if (lane >= d) inc += t2;
    }
    if (b < B) col[(size_t)b * stride] = inc - v + base;
    base += __shfl(inc, 63, 64);
  }
  if (lane == 0) *tot = base;
}

// ---------------- S2b: two single-wave shuffle scans + ticket zero ----------
__global__ __launch_bounds__(TPB) void scan2_v2(
    const unsigned* __restrict__ totC, unsigned* __restrict__ baseC, int SC, unsigned K,
    const unsigned* __restrict__ totF, unsigned* __restrict__ baseF, int SF, unsigned F,
    unsigned* __restrict__ ticket) {
  int lane = threadIdx.x & 63;
  int wv = threadIdx.x >> 6;
  if (wv == 0) {
    unsigned base = 0;
    for (int i0 = 0; i0 < SC; i0 += 64) {
      int i = i0 + lane;
      unsigned v = (i < SC) ? totC[i] : 0u;
      unsigned inc = v;
      #pragma unroll
      for (int d = 1; d < 64; d <<= 1) {
        unsigned t = __shfl_up(inc, d, 64);
        if (lane >= d) inc += t;
      }
      if (i < SC) baseC[i] = inc - v + base;
      base += __shfl(inc, 63, 64);
    }
    if (lane == 0) baseC[SC] = K;
  } else if (wv == 1) {
    unsigned base = 0;
    for (int i0 = 0; i0 < SF; i0 += 64) {
      int i = i0 + lane;
      unsigned v = (i < SF) ? totF[i] : 0u;
      unsigned inc = v;
      #pragma unroll
      for (int d = 1; d < 64; d <<= 1) {
        unsigned t = __shfl_up(inc, d, 64);
        if (lane >= d) inc += t;
      }
      if (i < SF) baseF[i] = inc - v + base;
      base += __shfl(inc, 63, 64);
    }
    if (lane == 0) baseF[SF] = F;
  } else if (threadIdx.x == 128) {
    *ticket = 0u;
  }
}

// ---------------- S3: LDS-rank scatter (both sorts) ----------------
__global__ __launch_bounds__(TPB) void sort_pass3(
    const int* __restrict__ cxg, const int* __restrict__ lix,
    const float* __restrict__ xc, const int* __restrict__ gix,
    const unsigned* __restrict__ cntC, const unsigned* __restrict__ cntF,
    const unsigned* __restrict__ baseC, const unsigned* __restrict__ baseF,
    float2* __restrict__ pl, unsigned* __restrict__ fpl,
    int K, int F, unsigned G, unsigned N) {
  __shared__ unsigned cC[MAXG];
  __shared__ unsigned cF[MAXN];
  for (int t = threadIdx.x; t < MAXG; t += TPB) cC[t] = 0;
  for (int t = threadIdx.x; t < MAXN; t += TPB) cF[t] = 0;
  __syncthreads();
  int i0 = blockIdx.x * CHUNK;
  size_t b = blockIdx.x;
  for (int t = threadIdx.x; t < CHUNK; t += TPB) {
    int i = i0 + t;
    if (i < K) {
      unsigned ix = (unsigned)cxg[i];
      unsigned g = ix % G, n = ix / G;
      unsigned r = atomicAdd(&cC[g], 1u);
      unsigned pos = baseC[g] + cntC[b * G + g] + r;
      pl[pos] = make_float2(xc[i], __uint_as_float((n << 16) | (unsigned)gix[i]));
    }
    if (i < F) {
      unsigned v = (unsigned)lix[i];
      unsigned n = v / G, g = v - n * G;
      unsigned r = atomicAdd(&cF[n], 1u);
      fpl[baseF[n] + cntF[b * N + n] + r] = (n << 16) | g;
    }
  }
}

// ---------------- D: cuts v6 — MFMA 16x16x32 bf16 ----------------
__global__ __launch_bounds__(TPB) void cuts_v6(
    const float2* __restrict__ pl, const unsigned short* __restrict__ latbf,
    const int* __restrict__ genes_oi, const float* __restrict__ logit_weight,
    const float4* __restrict__ gp, const unsigned* __restrict__ baseC,
    float* __restrict__ partials, unsigned G) {
  const int g = blockIdx.x;
  const int lane = threadIdx.x & 63;
  const int wv = threadIdx.x >> 6;
  const int quad = lane >> 4;
  const int r16 = lane & 15;

  const float* Wb = logit_weight + (size_t)genes_oi[g] * 2048;
  bf16x8 B0a, B1a, B0b, B1b;
  #pragma unroll
  for (int j = 0; j < 8; j++) {
    int l0 = quad * 8 + j;
    B0a[j] = (short)f2bf(Wb[l0 * 32 + r16]);
    B1a[j] = (short)f2bf(Wb[(l0 + 32) * 32 + r16]);
    B0b[j] = (short)f2bf(Wb[l0 * 32 + r16 + 16]);
    B1b[j] = (short)f2bf(Wb[(l0 + 32) * 32 + r16 + 16]);
  }

  const unsigned start = baseC[g], end = baseC[g + 1];
  const unsigned ntiles = (end - start + 15) >> 4;
  float lm = 0.f;

  for (unsigned t = wv; t < ntiles; t += 4) {
    unsigned kk0 = start + t * 16;
    unsigned idx = kk0 + r16;
    float2 p = pl[idx < end ? idx : start];
    unsigned u = __float_as_uint(p.y);
    const unsigned short* lb = latbf + (size_t)(u >> 16) * 64;
    bf16x8 A0 = *(const bf16x8*)(lb + quad * 8);
    bf16x8 A1 = *(const bf16x8*)(lb + 32 + quad * 8);

    f32x4 acc0 = {0.f, 0.f, 0.f, 0.f};
    f32x4 acc1 = {0.f, 0.f, 0.f, 0.f};
    acc0 = __builtin_amdgcn_mfma_f32_16x16x32_bf16(A0, B0a, acc0, 0, 0, 0);
    acc0 = __builtin_amdgcn_mfma_f32_16x16x32_bf16(A1, B1a, acc0, 0, 0, 0);
    acc1 = __builtin_amdgcn_mfma_f32_16x16x32_bf16(A0, B0b, acc1, 0, 0, 0);
    acc1 = __builtin_amdgcn_mfma_f32_16x16x32_bf16(A1, B1b, acc1, 0, 0, 0);

    #pragma unroll
    for (int r = 0; r < 4; r++) {
      int cut = quad * 4 + r;
      float xr = __shfl(p.x, cut, 64);
      unsigned ur = (unsigned)__shfl((int)u, cut, 64);
      unsigned gi = ur & 0xffffu;
      float4 q0 = gp[(size_t)gi * 32 + r16];
      float4 q1 = gp[(size_t)gi * 32 + r16 + 16];
      float t0 = q0.w + acc0[r], t1 = q1.w + acc1[r];
      float z0 = (xr - q0.x) * q0.y, z1 = (xr - q1.x) * q1.y;
      float u0 = t0 + fmaf(-0.5f * z0, z0, q0.z);
      float u1 = t1 + fmaf(-0.5f * z1, z1, q1.z);
      float e1 = __expf(u0) + __expf(u1);
      float e2 = __expf(t0) + __expf(t1);
      #pragma unroll
      for (int d = 1; d < 16; d <<= 1) {
        e1 += __shfl_xor(e1, d, 64);
        e2 += __shfl_xor(e2, d, 64);
      }
      if (r16 == 0 && (kk0 + (unsigned)cut) < end) lm += __logf(e1) - __logf(e2);
    }
  }
  float bs = block_reduce(lm);
  if (threadIdx.x == 0) partials[blockIdx.x] = bs;
}

// ---------------- E+F: Poisson with fused last-block finalize ----------------
__global__ __launch_bounds__(TPB) void pois_v5(
    const unsigned* __restrict__ fpl, const unsigned* __restrict__ baseF,
    const float* __restrict__ latent, const int* __restrict__ genes_oi,
    const int* __restrict__ cells_oi,
    const float* __restrict__ rho_weight, const float* __restrict__ rho_bias,
    const float* __restrict__ libsize,
    float* __restrict__ p1, int n1,
    float* __restrict__ p2, unsigned* __restrict__ ticket,
    float* __restrict__ out, int N, int G) {
  int n0 = blockIdx.x * 2;
  const int PB = gridDim.x;
  __shared__ unsigned cnt[2 * MAXG];
  for (int t = threadIdx.x; t < 2 * MAXG; t += TPB) cnt[t] = 0;
  __shared__ __align__(16) float lat[128];
  for (int t = threadIdx.x; t < 128; t += TPB) {
    int j = t >> 6, l = t & 63;
    lat[t] = (n0 + j < N) ? latent[(size_t)(n0 + j) * 64 + l] : 0.f;
  }
  __syncthreads();
  int nhi = min(n0 + 2, N);
  unsigned s0 = baseF[n0], e0 = baseF[nhi];
  for (unsigned i = s0 + threadIdx.x; i < e0; i += TPB) {
    unsigned v = fpl[i];
    unsigned j = (v >> 16) - (unsigned)n0, g = v & 0xffffu;
    atomicAdd(&cnt[j * MAXG + g], 1u);
  }
  __syncthreads();
  float lib0 = (n0 < N) ? libsize[cells_oi[n0]] : 0.f;
  float lib1 = (n0 + 1 < N) ? libsize[cells_oi[n0 + 1]] : 0.f;
  float sum = 0.f;
  for (int g = threadIdx.x; g < G; g += TPB) {
    long long gene = genes_oi[g];
    const float4* rw = (const float4*)(rho_weight + gene * 64);
    float r0 = 0.f, r1 = 0.f;
    #pragma unroll
    for (int i = 0; i < 16; i++) {
      float4 wv = rw[i];
      float4 l0 = *(const float4*)(&lat[i * 4]);
      float4 l1 = *(const float4*)(&lat[64 + i * 4]);
      r0 = fmaf(wv.x, l0.x, r0); r0 = fmaf(wv.y, l0.y, r0);
      r0 = fmaf(wv.z, l0.z, r0); r0 = fmaf(wv.w, l0.w, r0);
      r1 = fmaf(wv.x, l1.x, r1); r1 = fmaf(wv.y, l1.y, r1);
      r1 = fmaf(wv.z, l1.z, r1); r1 = fmaf(wv.w, l1.w, r1);
    }
    float rb = rho_bias[gene];
    if (n0 < N) {
      float fe = rb * __expf(r0) * lib0;
      unsigned c = cnt[g];
      float term = -fe;
      if (c) {
        float lf = 0.f;
        for (unsigned q2 = 2; q2 <= c; q2++) lf += __logf((float)q2);
        term += (float)c * __logf(fe) - lf;
      }
      sum += term;
    }
    if (n0 + 1 < N) {
      float fe = rb * __expf(r1) * lib1;
      unsigned c = cnt[MAXG + g];
      float term = -fe;
      if (c) {
        float lf = 0.f;
        for (unsigned q2 = 2; q2 <= c; q2++) lf += __logf((float)q2);
        term += (float)c * __logf(fe) - lf;
      }
      sum += term;
    }
  }
  float bs = block_reduce(sum);
  __shared__ unsigned slast;
  if (threadIdx.x == 0) {
    p2[blockIdx.x] = bs;
    __threadfence();
    slast = atomicAdd(ticket, 1u);
  }
  __syncthreads();
  if (slast == (unsigned)(PB - 1)) {
    __threadfence();
    float s = 0.f;
    for (int i = threadIdx.x; i < n1; i += TPB) s += p1[i];
    for (int i = threadIdx.x; i < PB; i += TPB) s += p2[i];
    float tot = block_reduce(s);
    if (threadIdx.x == 0) out[0] = -tot;
  }
}

extern "C" void kernel_launch(void* const* d_in, const int* in_sizes, int n_in,
                              void* d_out, int out_size, void* d_ws, size_t ws_size,
                              hipStream_t stream) {
  const int*   lix          = (const int*)d_in[0];
  const float* xc           = (const float*)d_in[1];
  const float* latent       = (const float*)d_in[2];
  const int*   genes_oi     = (const int*)d_in[3];
  const int*   cells_oi     = (const int*)d_in[4];
  const int*   cxg          = (const int*)d_in[5];
  const int*   gix          = (const int*)d_in[6];
  const float* loc_w        = (const float*)d_in[9];
  const float* scale_w      = (const float*)d_in[10];
  const float* logit_w      = (const float*)d_in[11];
  const float* logit_weight = (const float*)d_in[12];
  const float* rho_weight   = (const float*)d_in[13];
  const float* rho_bias     = (const float*)d_in[14];
  const float* libsize      = (const float*)d_in[15];
  float* out = (float*)d_out;

  const int F = in_sizes[0];
  const int K = in_sizes[1];
  const int N = in_sizes[2] / 64;
  const int G = in_sizes[3];
  const int NL = N * 64;

  const int M = (K > F) ? K : F;
  const int B = (M + CHUNK - 1) / CHUNK;           // sort chunks
  const int PB = (N + 1) / 2;                      // pois blocks
  const int GPB = (G * 32 + NL + TPB - 1) / TPB;   // gene-param blocks

  size_t off = 0;
  auto alloc = [&](size_t bytes) {
    size_t o = off;
    off = (off + bytes + 255) & ~(size_t)255;
    return o;
  };
  size_t cntC_off  = alloc((size_t)B * G * 4);
  size_t cntF_off  = alloc((size_t)B * N * 4);
  size_t totC_off  = alloc((size_t)G * 4);
  size_t totF_off  = alloc((size_t)N * 4);
  size_t baseC_off = alloc((size_t)(G + 1) * 4);
  size_t baseF_off = alloc((size_t)(N + 1) * 4);
  size_t pl_off    = alloc((size_t)K * 8);
  size_t fpl_off   = alloc((size_t)F * 4);
  size_t gp_off    = alloc((size_t)G * 32 * 16);
  size_t lb_off    = alloc((size_t)NL * 2);
  size_t p1_off    = alloc((size_t)G * 4);
  size_t p2_off    = alloc((size_t)PB * 4);
  size_t tk_off    = alloc(4);
  (void)ws_size;   // ~22 MB needed

  char* ws = (char*)d_ws;
  unsigned* cntC  = (unsigned*)(ws + cntC_off);
  unsigned* cntF  = (unsigned*)(ws + cntF_off);
  unsigned* totC  = (unsigned*)(ws + totC_off);
  unsigned* totF  = (unsigned*)(ws + totF_off);
  unsigned* baseC = (unsigned*)(ws + baseC_off);
  unsigned* baseF = (unsigned*)(ws + baseF_off);
  float2*   pl    = (float2*)(ws + pl_off);
  unsigned* fpl   = (unsigned*)(ws + fpl_off);
  float4*   gp    = (float4*)(ws + gp_off);
  unsigned short* latbf = (unsigned short*)(ws + lb_off);
  float*    p1    = (float*)(ws + p1_off);
  float*    p2    = (float*)(ws + p2_off);
  unsigned* ticket = (unsigned*)(ws + tk_off);

  prep_hist_kernel<<<B + GPB, TPB, 0, stream>>>(
      cxg, lix, cntC, cntF, genes_oi, loc_w, scale_w, logit_w, latent,
      gp, latbf, K, F, (unsigned)G, (unsigned)N, B, NL);
  colscan_v2<<<(G + N + 3) / 4, TPB, 0, stream>>>(
      cntC, cntF, totC, totF, B, (unsigned)G, (unsigned)N);
  scan2_v2<<<1, TPB, 0, stream>>>(totC, baseC, G, (unsigned)K,
                                  totF, baseF, N, (unsigned)F, ticket);
  sort_pass3<<<B, TPB, 0, stream>>>(cxg, lix, xc, gix, cntC, cntF, baseC, baseF,
                                    pl, fpl, K, F, (unsigned)G, (unsigned)N);
  cuts_v6<<<G, TPB, 0, stream>>>(pl, latbf, genes_oi, logit_weight, gp, baseC, p1, (unsigned)G);
  pois_v5<<<PB, TPB, 0, stream>>>(fpl, baseF, latent, genes_oi, cells_oi,
                                  rho_weight, rho_bias, libsize,
                                  p1, G, p2, ticket, out, N, G);
}